// Round 2
// baseline (1099.765 us; speedup 1.0000x reference)
//
#include <hip/hip_runtime.h>

#define TSTEPS 512   // LSTM sequence length (2048/4)
#define HID    64

typedef float v2f __attribute__((ext_vector_type(2)));

__device__ __forceinline__ v2f pkfma(v2f a, v2f b, v2f c) {
#if __has_builtin(__builtin_elementwise_fma)
  return __builtin_elementwise_fma(a, b, c);
#else
  return (v2f){fmaf(a.x, b.x, c.x), fmaf(a.y, b.y, c.y)};
#endif
}

__device__ __forceinline__ float sigm(float x) {
  return 1.0f / (1.0f + __expf(-x));
}
__device__ __forceinline__ float tanh_(float x) {
  return 1.0f - 2.0f / (1.0f + __expf(2.0f * x));
}

// ---------------------------------------------------------------------------
// Kernel 1: conv1 (3->16, k=3, same) + maxpool2.  x:[256,2048,3] -> t1:[256,1024,16]
// ---------------------------------------------------------------------------
__global__ __launch_bounds__(256) void conv1_pool(
    const float* __restrict__ x, const float* __restrict__ w,
    const float* __restrict__ bias, float* __restrict__ out) {
  __shared__ float ws[144];
  __shared__ float bs[16];
  const int tid = threadIdx.x;
  if (tid < 144) ws[tid] = w[tid];
  if (tid < 16)  bs[tid] = bias[tid];
  __syncthreads();

  const int idx = blockIdx.x * 256 + tid;   // b*1024 + t2
  const int b  = idx >> 10;
  const int t2 = idx & 1023;
  const float* xb = x + (size_t)b * 2048 * 3;
  const int p0 = 2 * t2;

  float xv[4][3];
#pragma unroll
  for (int j = 0; j < 4; ++j) {
    const int p = p0 - 1 + j;
    const bool ok = (p >= 0) && (p < 2048);
#pragma unroll
    for (int c = 0; c < 3; ++c) xv[j][c] = ok ? xb[p * 3 + c] : 0.0f;
  }

  float4 o4[4];
  float* op = (float*)o4;
#pragma unroll
  for (int o = 0; o < 16; ++o) {
    float s0 = bs[o], s1 = bs[o];
#pragma unroll
    for (int c = 0; c < 3; ++c) {
#pragma unroll
      for (int k = 0; k < 3; ++k) {
        const float wv = ws[(o * 3 + c) * 3 + k];
        s0 = fmaf(xv[k][c],     wv, s0);
        s1 = fmaf(xv[k + 1][c], wv, s1);
      }
    }
    op[o] = fmaxf(s0, s1);
  }
  float4* dst = (float4*)(out + (size_t)idx * 16);
  dst[0] = o4[0]; dst[1] = o4[1]; dst[2] = o4[2]; dst[3] = o4[3];
}

// ---------------------------------------------------------------------------
// Kernel 2: conv2 (16->32, k=3, same) + maxpool2. t1:[256,1024,16] -> feat:[256,512,32]
// ---------------------------------------------------------------------------
__global__ __launch_bounds__(256) void conv2_pool(
    const float* __restrict__ t1, const float* __restrict__ w,
    const float* __restrict__ bias, float* __restrict__ out) {
  __shared__ float ws[1536];
  __shared__ float bs[32];
  const int tid = threadIdx.x;
  for (int i = tid; i < 1536; i += 256) ws[i] = w[i];
  if (tid < 32) bs[tid] = bias[tid];
  __syncthreads();

  const int idx = blockIdx.x * 256 + tid;   // b*512 + t2
  const int b  = idx >> 9;
  const int t2 = idx & 511;
  const float* tb = t1 + (size_t)b * 1024 * 16;
  const int p0 = 2 * t2;

  float4 r4[4][4];
  float* r = (float*)r4;
#pragma unroll
  for (int j = 0; j < 4; ++j) {
    const int p = p0 - 1 + j;
    if (p >= 0 && p < 1024) {
      const float4* s = (const float4*)(tb + p * 16);
      r4[j][0] = s[0]; r4[j][1] = s[1]; r4[j][2] = s[2]; r4[j][3] = s[3];
    } else {
      const float4 z = {0.f, 0.f, 0.f, 0.f};
      r4[j][0] = z; r4[j][1] = z; r4[j][2] = z; r4[j][3] = z;
    }
  }

  float4 o4[8];
  float* op = (float*)o4;
#pragma unroll 4
  for (int o = 0; o < 32; ++o) {
    float s0 = bs[o], s1 = bs[o];
    const float* wo = &ws[o * 48];
#pragma unroll
    for (int c = 0; c < 16; ++c) {
      const float w0 = wo[c * 3], w1 = wo[c * 3 + 1], w2 = wo[c * 3 + 2];
      s0 = fmaf(r[0 * 16 + c], w0, s0);
      s0 = fmaf(r[1 * 16 + c], w1, s0);
      s0 = fmaf(r[2 * 16 + c], w2, s0);
      s1 = fmaf(r[1 * 16 + c], w0, s1);
      s1 = fmaf(r[2 * 16 + c], w1, s1);
      s1 = fmaf(r[3 * 16 + c], w2, s1);
    }
    op[o] = fmaxf(s0, s1);
  }
  float4* dst = (float4*)(out + (size_t)idx * 32);
#pragma unroll
  for (int q = 0; q < 8; ++q) dst[q] = o4[q];
}

// ---------------------------------------------------------------------------
// Kernel 3: fused 2-layer LSTM + fc.  One block per batch element, 4 waves
// (256 threads) — one wave per SIMD, 1 wave/SIMD occupancy so each lane can
// hold all 3 weight rows (192 floats) in VGPRs.
//
//   wave w (= tid>>6) computes gate-type w (PyTorch order i,f,g,o) for all
//   64 units (unit = lane) of layer0 step t AND layer1 step t-1 (pipelined).
//   ONE barrier per step: gates -> pre[] (double-buffered on t&1) -> barrier
//   -> every wave redundantly computes the h/c update (c0,c1 private regs per
//   wave) and writes h0,h1 into its OWN LDS slot (hbuf[w]) — read back next
//   step by the same wave, so no second barrier is needed.
//   Dot products are v2f packed -> v_pk_fma_f32 (2 FMA/inst).
// ---------------------------------------------------------------------------
__global__ __launch_bounds__(256, 1) void lstm_fused(
    const float* __restrict__ feat,
    const float* __restrict__ w_ih0, const float* __restrict__ w_hh0,
    const float* __restrict__ b_ih0, const float* __restrict__ b_hh0,
    const float* __restrict__ w_ih1, const float* __restrict__ w_hh1,
    const float* __restrict__ b_ih1, const float* __restrict__ b_hh1,
    const float* __restrict__ fc_w, const float* __restrict__ fc_b,
    float* __restrict__ out) {
  __shared__ float4 featL[256 * 8];    // 32 KB: feat rows [tbase, tbase+256)
  __shared__ float  pre[2][2][256];    // [t&1][layer][gate-row], 4 KB
  __shared__ float  hbuf[4][128];      // per-wave private: [0..63]=h0, [64..127]=h1

  const int tid = threadIdx.x;
  const int w   = tid >> 6;   // gate type
  const int u   = tid & 63;   // unit
  const int r   = tid;        // row index in 4H (= w*64+u)
  const int b   = blockIdx.x;

  // ---- weight rows into registers (v2 packed) ----
  v2f wx0[16], wh0[32], wi1[32], wh1[32];
  {
    const float4* s = (const float4*)(w_ih0 + (size_t)r * 32);
#pragma unroll
    for (int k = 0; k < 8; ++k) {
      float4 v = s[k];
      wx0[2 * k]     = (v2f){v.x, v.y};
      wx0[2 * k + 1] = (v2f){v.z, v.w};
    }
  }
  {
    const float4* s = (const float4*)(w_hh0 + (size_t)r * 64);
#pragma unroll
    for (int k = 0; k < 16; ++k) {
      float4 v = s[k];
      wh0[2 * k]     = (v2f){v.x, v.y};
      wh0[2 * k + 1] = (v2f){v.z, v.w};
    }
  }
  {
    const float4* s = (const float4*)(w_ih1 + (size_t)r * 64);
#pragma unroll
    for (int k = 0; k < 16; ++k) {
      float4 v = s[k];
      wi1[2 * k]     = (v2f){v.x, v.y};
      wi1[2 * k + 1] = (v2f){v.z, v.w};
    }
  }
  {
    const float4* s = (const float4*)(w_hh1 + (size_t)r * 64);
#pragma unroll
    for (int k = 0; k < 16; ++k) {
      float4 v = s[k];
      wh1[2 * k]     = (v2f){v.x, v.y};
      wh1[2 * k + 1] = (v2f){v.z, v.w};
    }
  }
  const float bias0 = b_ih0[r] + b_hh0[r];
  const float bias1 = b_ih1[r] + b_hh1[r];

  // own-wave h state init (no cross-wave access -> no barrier needed)
  hbuf[w][u]      = 0.0f;
  hbuf[w][64 + u] = 0.0f;

  const float4* fg = (const float4*)(feat + (size_t)b * TSTEPS * 32);
  float c0 = 0.0f, c1 = 0.0f;

  for (int t = 0; t <= TSTEPS; ++t) {
    // stage feat rows in 256-step halves (block-uniform branch)
    if ((t & 255) == 0 && t < TSTEPS) {
      if (t) __syncthreads();          // all waves past their t-1 featL reads
      const float4* src = fg + t * 8;
#pragma unroll
      for (int k = 0; k < 8; ++k) featL[tid + k * 256] = src[tid + k * 256];
      __syncthreads();                 // copy visible before gate reads
    }

    // ---------- gate phase ----------
    if (t < TSTEPS) {
      const v2f* xv  = (const v2f*)&featL[(t & 255) * 8];
      const v2f* h0p = (const v2f*)&hbuf[w][0];
      v2f a0 = {0.f, 0.f}, a1 = {0.f, 0.f}, a2 = {0.f, 0.f}, a3 = {0.f, 0.f};
#pragma unroll
      for (int k = 0; k < 16; k += 4) {
        a0 = pkfma(wx0[k],     xv[k],     a0);
        a1 = pkfma(wx0[k + 1], xv[k + 1], a1);
        a2 = pkfma(wx0[k + 2], xv[k + 2], a2);
        a3 = pkfma(wx0[k + 3], xv[k + 3], a3);
      }
#pragma unroll
      for (int k = 0; k < 32; k += 4) {
        a0 = pkfma(wh0[k],     h0p[k],     a0);
        a1 = pkfma(wh0[k + 1], h0p[k + 1], a1);
        a2 = pkfma(wh0[k + 2], h0p[k + 2], a2);
        a3 = pkfma(wh0[k + 3], h0p[k + 3], a3);
      }
      const v2f s = (a0 + a1) + (a2 + a3);
      pre[t & 1][0][r] = s.x + s.y + bias0;
    }
    if (t >= 1) {
      const v2f* h0p = (const v2f*)&hbuf[w][0];   // h0[t-1]
      const v2f* h1p = (const v2f*)&hbuf[w][64];  // h1[t-2]
      v2f a0 = {0.f, 0.f}, a1 = {0.f, 0.f}, a2 = {0.f, 0.f}, a3 = {0.f, 0.f};
#pragma unroll
      for (int k = 0; k < 32; k += 4) {
        a0 = pkfma(wi1[k],     h0p[k],     a0);
        a1 = pkfma(wi1[k + 1], h0p[k + 1], a1);
        a2 = pkfma(wi1[k + 2], h0p[k + 2], a2);
        a3 = pkfma(wi1[k + 3], h0p[k + 3], a3);
      }
#pragma unroll
      for (int k = 0; k < 32; k += 4) {
        a0 = pkfma(wh1[k],     h1p[k],     a0);
        a1 = pkfma(wh1[k + 1], h1p[k + 1], a1);
        a2 = pkfma(wh1[k + 2], h1p[k + 2], a2);
        a3 = pkfma(wh1[k + 3], h1p[k + 3], a3);
      }
      const v2f s = (a0 + a1) + (a2 + a3);
      pre[t & 1][1][r] = s.x + s.y + bias1;
    }

    __syncthreads();   // the ONE barrier: pre[] visible to all waves

    // ---------- update phase (all 4 waves, redundant) ----------
    if (t < TSTEPS) {
      const float pi = pre[t & 1][0][u];
      const float pf = pre[t & 1][0][64 + u];
      const float pg = pre[t & 1][0][128 + u];
      const float po = pre[t & 1][0][192 + u];
      const float i = sigm(pi), f = sigm(pf);
      const float g = tanh_(pg), o = sigm(po);
      c0 = fmaf(f, c0, i * g);
      hbuf[w][u] = o * tanh_(c0);          // h0[t], own-wave slot
    }
    if (t >= 1) {
      const float pi = pre[t & 1][1][u];
      const float pf = pre[t & 1][1][64 + u];
      const float pg = pre[t & 1][1][128 + u];
      const float po = pre[t & 1][1][192 + u];
      const float i = sigm(pi), f = sigm(pf);
      const float g = tanh_(pg), o = sigm(po);
      c1 = fmaf(f, c1, i * g);
      hbuf[w][64 + u] = o * tanh_(c1);     // h1[t-1], own-wave slot
    }
  }

  // fc epilogue: h1[T-1] sits in hbuf[0][64..127] (wave 0 wrote it; lanes 0..4
  // of wave 0 read it — same-wave ordering, no barrier needed)
  if (tid < 5) {
    const float* h = &hbuf[0][64];
    float s = fc_b[tid];
    const float* wrow = fc_w + tid * HID;
#pragma unroll
    for (int j = 0; j < HID; ++j) s = fmaf(wrow[j], h[j], s);
    out[b * 5 + tid] = s;
  }
}

// ---------------------------------------------------------------------------
extern "C" void kernel_launch(void* const* d_in, const int* in_sizes, int n_in,
                              void* d_out, int out_size, void* d_ws, size_t ws_size,
                              hipStream_t stream) {
  (void)in_sizes; (void)n_in; (void)out_size; (void)ws_size;
  const float* x    = (const float*)d_in[0];
  const float* c1w  = (const float*)d_in[1];
  const float* c1b  = (const float*)d_in[2];
  const float* c2w  = (const float*)d_in[3];
  const float* c2b  = (const float*)d_in[4];
  const float* wih0 = (const float*)d_in[5];
  const float* whh0 = (const float*)d_in[6];
  const float* bih0 = (const float*)d_in[7];
  const float* bhh0 = (const float*)d_in[8];
  const float* wih1 = (const float*)d_in[9];
  const float* whh1 = (const float*)d_in[10];
  const float* bih1 = (const float*)d_in[11];
  const float* bhh1 = (const float*)d_in[12];
  const float* fcw  = (const float*)d_in[13];
  const float* fcb  = (const float*)d_in[14];
  float* out = (float*)d_out;

  float* t1   = (float*)d_ws;                       // [256,1024,16] = 16 MB
  float* feat = t1 + (size_t)256 * 1024 * 16;       // [256,512,32]  = 16 MB

  conv1_pool<<<1024, 256, 0, stream>>>(x, c1w, c1b, t1);
  conv2_pool<<<512, 256, 0, stream>>>(t1, c2w, c2b, feat);
  lstm_fused<<<256, 256, 0, stream>>>(feat, wih0, whh0, bih0, bhh0,
                                      wih1, whh1, bih1, bhh1, fcw, fcb, out);
}

// Round 4
// 711.802 us; speedup vs baseline: 1.5450x; 1.5450x over previous
//
#include <hip/hip_runtime.h>

#define TSTEPS 512   // LSTM sequence length (2048/4)
#define HID    64

typedef float v2f __attribute__((ext_vector_type(2)));

__device__ __forceinline__ v2f pkfma(v2f a, v2f b, v2f c) {
#if __has_builtin(__builtin_elementwise_fma)
  return __builtin_elementwise_fma(a, b, c);
#else
  return (v2f){fmaf(a.x, b.x, c.x), fmaf(a.y, b.y, c.y)};
#endif
}

__device__ __forceinline__ float sigm(float x) {
  return 1.0f / (1.0f + __expf(-x));
}
__device__ __forceinline__ float tanh_(float x) {
  return 1.0f - 2.0f / (1.0f + __expf(2.0f * x));
}

// ---------------------------------------------------------------------------
// Kernel 1: conv1 (3->16, k=3, same) + maxpool2.  x:[256,2048,3] -> t1:[256,1024,16]
// ---------------------------------------------------------------------------
__global__ __launch_bounds__(256) void conv1_pool(
    const float* __restrict__ x, const float* __restrict__ w,
    const float* __restrict__ bias, float* __restrict__ out) {
  __shared__ float ws[144];
  __shared__ float bs[16];
  const int tid = threadIdx.x;
  if (tid < 144) ws[tid] = w[tid];
  if (tid < 16)  bs[tid] = bias[tid];
  __syncthreads();

  const int idx = blockIdx.x * 256 + tid;   // b*1024 + t2
  const int b  = idx >> 10;
  const int t2 = idx & 1023;
  const float* xb = x + (size_t)b * 2048 * 3;
  const int p0 = 2 * t2;

  float xv[4][3];
#pragma unroll
  for (int j = 0; j < 4; ++j) {
    const int p = p0 - 1 + j;
    const bool ok = (p >= 0) && (p < 2048);
#pragma unroll
    for (int c = 0; c < 3; ++c) xv[j][c] = ok ? xb[p * 3 + c] : 0.0f;
  }

  float4 o4[4];
  float* op = (float*)o4;
#pragma unroll
  for (int o = 0; o < 16; ++o) {
    float s0 = bs[o], s1 = bs[o];
#pragma unroll
    for (int c = 0; c < 3; ++c) {
#pragma unroll
      for (int k = 0; k < 3; ++k) {
        const float wv = ws[(o * 3 + c) * 3 + k];
        s0 = fmaf(xv[k][c],     wv, s0);
        s1 = fmaf(xv[k + 1][c], wv, s1);
      }
    }
    op[o] = fmaxf(s0, s1);
  }
  float4* dst = (float4*)(out + (size_t)idx * 16);
  dst[0] = o4[0]; dst[1] = o4[1]; dst[2] = o4[2]; dst[3] = o4[3];
}

// ---------------------------------------------------------------------------
// Kernel 2: conv2 (16->32, k=3, same) + maxpool2. t1:[256,1024,16] -> feat:[256,512,32]
// ---------------------------------------------------------------------------
__global__ __launch_bounds__(256) void conv2_pool(
    const float* __restrict__ t1, const float* __restrict__ w,
    const float* __restrict__ bias, float* __restrict__ out) {
  __shared__ float ws[1536];
  __shared__ float bs[32];
  const int tid = threadIdx.x;
  for (int i = tid; i < 1536; i += 256) ws[i] = w[i];
  if (tid < 32) bs[tid] = bias[tid];
  __syncthreads();

  const int idx = blockIdx.x * 256 + tid;   // b*512 + t2
  const int b  = idx >> 9;
  const int t2 = idx & 511;
  const float* tb = t1 + (size_t)b * 1024 * 16;
  const int p0 = 2 * t2;

  float4 r4[4][4];
  float* r = (float*)r4;
#pragma unroll
  for (int j = 0; j < 4; ++j) {
    const int p = p0 - 1 + j;
    if (p >= 0 && p < 1024) {
      const float4* s = (const float4*)(tb + p * 16);
      r4[j][0] = s[0]; r4[j][1] = s[1]; r4[j][2] = s[2]; r4[j][3] = s[3];
    } else {
      const float4 z = {0.f, 0.f, 0.f, 0.f};
      r4[j][0] = z; r4[j][1] = z; r4[j][2] = z; r4[j][3] = z;
    }
  }

  float4 o4[8];
  float* op = (float*)o4;
#pragma unroll 4
  for (int o = 0; o < 32; ++o) {
    float s0 = bs[o], s1 = bs[o];
    const float* wo = &ws[o * 48];
#pragma unroll
    for (int c = 0; c < 16; ++c) {
      const float w0 = wo[c * 3], w1 = wo[c * 3 + 1], w2 = wo[c * 3 + 2];
      s0 = fmaf(r[0 * 16 + c], w0, s0);
      s0 = fmaf(r[1 * 16 + c], w1, s0);
      s0 = fmaf(r[2 * 16 + c], w2, s0);
      s1 = fmaf(r[1 * 16 + c], w0, s1);
      s1 = fmaf(r[2 * 16 + c], w1, s1);
      s1 = fmaf(r[3 * 16 + c], w2, s1);
    }
    op[o] = fmaxf(s0, s1);
  }
  float4* dst = (float4*)(out + (size_t)idx * 32);
#pragma unroll
  for (int q = 0; q < 8; ++q) dst[q] = o4[q];
}

// ---------------------------------------------------------------------------
// Kernel 3: fused 2-layer LSTM + fc.  One block per batch element, 8 waves
// (512 threads, 2 waves/SIMD).  Thread = one gate-row: waves 0-3 own layer0
// rows (tid), waves 4-7 own layer1 rows (tid-256).  Weight footprint per
// thread <= 64 v2f = 128 VGPRs (wA/wB reused across the two layer paths) so
// the allocator keeps them register-resident (round-2 spilled at 224).
//
// One barrier per step: gate pre-activations -> pre[t&1][tid] -> barrier ->
// every wave redundantly computes the layer0 cell update (layer1 waves also
// the layer1 update) with private c-state, writing h into its OWN LDS slot
// hbuf[wave] (read back only by the same wave -> no second barrier).
// Activation reads are wave-uniform -> LDS broadcast, conflict-free.
// ---------------------------------------------------------------------------
__global__ __launch_bounds__(512, 2) void lstm_fused(
    const float* __restrict__ feat,
    const float* __restrict__ w_ih0, const float* __restrict__ w_hh0,
    const float* __restrict__ b_ih0, const float* __restrict__ b_hh0,
    const float* __restrict__ w_ih1, const float* __restrict__ w_hh1,
    const float* __restrict__ b_ih1, const float* __restrict__ b_hh1,
    const float* __restrict__ fc_w, const float* __restrict__ fc_b,
    float* __restrict__ out) {
  __shared__ float4 featL[2048];      // 32 KB: feat rows [tbase, tbase+256)
  __shared__ float  pre[2][512];      // 4 KB, double-buffered on t&1
  __shared__ float  hbuf[8][128];     // per-wave private: [0..63]=h0, [64..127]=h1

  const int tid = threadIdx.x;
  const int wv  = tid >> 6;           // wave id 0..7
  const int u   = tid & 63;           // lane / unit
  const int b   = blockIdx.x;
  const bool isL1 = (wv >= 4);
  const int r = isL1 ? (tid - 256) : tid;   // row within this layer's 4H

  // ---- weight rows -> registers (direct v2f loads, no local-array casts) ----
  v2f wA[32], wB[32];   // L0: wA=w_hh0 row (64f), wB[0..15]=w_ih0 row (32f)
                        // L1: wA=w_ih1 row (64f), wB=w_hh1 row (64f)
  float bias;
  if (!isL1) {
    const v2f* h = (const v2f*)(w_hh0 + (size_t)r * 64);
#pragma unroll
    for (int k = 0; k < 32; ++k) wA[k] = h[k];
    const v2f* xw = (const v2f*)(w_ih0 + (size_t)r * 32);
#pragma unroll
    for (int k = 0; k < 16; ++k) wB[k] = xw[k];
#pragma unroll
    for (int k = 16; k < 32; ++k) wB[k] = (v2f){0.f, 0.f};
    bias = b_ih0[r] + b_hh0[r];
  } else {
    const v2f* iw = (const v2f*)(w_ih1 + (size_t)r * 64);
#pragma unroll
    for (int k = 0; k < 32; ++k) wA[k] = iw[k];
    const v2f* h = (const v2f*)(w_hh1 + (size_t)r * 64);
#pragma unroll
    for (int k = 0; k < 32; ++k) wB[k] = h[k];
    bias = b_ih1[r] + b_hh1[r];
  }

  // own-wave h-state init (only read by own wave before first barrier)
  hbuf[wv][u]      = 0.0f;
  hbuf[wv][64 + u] = 0.0f;

  const float4* fg = (const float4*)(feat + (size_t)b * TSTEPS * 32);
  float c0 = 0.0f, c1 = 0.0f;

  for (int t = 0; t <= TSTEPS; ++t) {
    // stage feat rows in 256-step halves (block-uniform branch)
    if ((t & 255) == 0 && t < TSTEPS) {
      if (t) __syncthreads();          // all waves done reading previous half
      const float4* src = fg + t * 8;
#pragma unroll
      for (int k = 0; k < 4; ++k) featL[tid + k * 512] = src[tid + k * 512];
      __syncthreads();                 // copy visible before gate reads
    }

    // ---------- gate phase ----------
    if (!isL1) {
      if (t < TSTEPS) {
        const float4* xt = &featL[(t & 255) * 8];
        const float4* hp = (const float4*)&hbuf[wv][0];
        v2f a0 = {0.f,0.f}, a1 = {0.f,0.f}, a2 = {0.f,0.f}, a3 = {0.f,0.f};
#pragma unroll
        for (int k = 0; k < 8; k += 2) {          // x-part: 8 float4, wB[0..15]
          const float4 v0 = xt[k], v1 = xt[k + 1];
          a0 = pkfma(wB[2*k],     (v2f){v0.x, v0.y}, a0);
          a1 = pkfma(wB[2*k + 1], (v2f){v0.z, v0.w}, a1);
          a2 = pkfma(wB[2*k + 2], (v2f){v1.x, v1.y}, a2);
          a3 = pkfma(wB[2*k + 3], (v2f){v1.z, v1.w}, a3);
        }
#pragma unroll
        for (int k = 0; k < 16; k += 2) {         // h0-part: 16 float4, wA[0..31]
          const float4 v0 = hp[k], v1 = hp[k + 1];
          a0 = pkfma(wA[2*k],     (v2f){v0.x, v0.y}, a0);
          a1 = pkfma(wA[2*k + 1], (v2f){v0.z, v0.w}, a1);
          a2 = pkfma(wA[2*k + 2], (v2f){v1.x, v1.y}, a2);
          a3 = pkfma(wA[2*k + 3], (v2f){v1.z, v1.w}, a3);
        }
        const v2f s = (a0 + a1) + (a2 + a3);
        pre[t & 1][tid] = s.x + s.y + bias;
      }
    } else {
      if (t >= 1) {
        const float4* h0p = (const float4*)&hbuf[wv][0];    // h0[t-1]
        const float4* h1p = (const float4*)&hbuf[wv][64];   // h1[t-2]
        v2f a0 = {0.f,0.f}, a1 = {0.f,0.f}, a2 = {0.f,0.f}, a3 = {0.f,0.f};
#pragma unroll
        for (int k = 0; k < 16; k += 2) {         // h0-part: wA
          const float4 v0 = h0p[k], v1 = h0p[k + 1];
          a0 = pkfma(wA[2*k],     (v2f){v0.x, v0.y}, a0);
          a1 = pkfma(wA[2*k + 1], (v2f){v0.z, v0.w}, a1);
          a2 = pkfma(wA[2*k + 2], (v2f){v1.x, v1.y}, a2);
          a3 = pkfma(wA[2*k + 3], (v2f){v1.z, v1.w}, a3);
        }
#pragma unroll
        for (int k = 0; k < 16; k += 2) {         // h1-part: wB
          const float4 v0 = h1p[k], v1 = h1p[k + 1];
          a0 = pkfma(wB[2*k],     (v2f){v0.x, v0.y}, a0);
          a1 = pkfma(wB[2*k + 1], (v2f){v0.z, v0.w}, a1);
          a2 = pkfma(wB[2*k + 2], (v2f){v1.x, v1.y}, a2);
          a3 = pkfma(wB[2*k + 3], (v2f){v1.z, v1.w}, a3);
        }
        const v2f s = (a0 + a1) + (a2 + a3);
        pre[t & 1][tid] = s.x + s.y + bias;       // rows 256..511
      }
    }

    __syncthreads();   // the ONE barrier: pre[] visible to all waves

    // ---------- update phase ----------
    if (t < TSTEPS) {   // layer0 update (every wave, private copy)
      const float* p = pre[t & 1];
      const float i = sigm(p[u]),       f = sigm(p[64 + u]);
      const float g = tanh_(p[128 + u]), o = sigm(p[192 + u]);
      c0 = fmaf(f, c0, i * g);
      hbuf[wv][u] = o * tanh_(c0);                // h0[t], own slot
    }
    if (isL1 && t >= 1) {   // layer1 update (only layer1 waves need h1)
      const float* p = pre[t & 1] + 256;
      const float i = sigm(p[u]),       f = sigm(p[64 + u]);
      const float g = tanh_(p[128 + u]), o = sigm(p[192 + u]);
      c1 = fmaf(f, c1, i * g);
      hbuf[wv][64 + u] = o * tanh_(c1);           // h1[t-1], own slot
    }
  }

  // fc epilogue: wave 4 wrote h1[T-1] into hbuf[4][64..127]; lanes 0..4 of
  // wave 4 read it (same-wave ordering, no barrier needed)
  if (tid >= 256 && tid < 261) {
    const int j = tid - 256;
    const float* h = &hbuf[4][64];
    float s = fc_b[j];
    const float* wr = fc_w + j * HID;
#pragma unroll
    for (int k = 0; k < HID; ++k) s = fmaf(wr[k], h[k], s);
    out[b * 5 + j] = s;
  }
}

// ---------------------------------------------------------------------------
extern "C" void kernel_launch(void* const* d_in, const int* in_sizes, int n_in,
                              void* d_out, int out_size, void* d_ws, size_t ws_size,
                              hipStream_t stream) {
  (void)in_sizes; (void)n_in; (void)out_size; (void)ws_size;
  const float* x    = (const float*)d_in[0];
  const float* c1w  = (const float*)d_in[1];
  const float* c1b  = (const float*)d_in[2];
  const float* c2w  = (const float*)d_in[3];
  const float* c2b  = (const float*)d_in[4];
  const float* wih0 = (const float*)d_in[5];
  const float* whh0 = (const float*)d_in[6];
  const float* bih0 = (const float*)d_in[7];
  const float* bhh0 = (const float*)d_in[8];
  const float* wih1 = (const float*)d_in[9];
  const float* whh1 = (const float*)d_in[10];
  const float* bih1 = (const float*)d_in[11];
  const float* bhh1 = (const float*)d_in[12];
  const float* fcw  = (const float*)d_in[13];
  const float* fcb  = (const float*)d_in[14];
  float* out = (float*)d_out;

  float* t1   = (float*)d_ws;                       // [256,1024,16] = 16 MB
  float* feat = t1 + (size_t)256 * 1024 * 16;       // [256,512,32]  = 16 MB

  conv1_pool<<<1024, 256, 0, stream>>>(x, c1w, c1b, t1);
  conv2_pool<<<512, 256, 0, stream>>>(t1, c2w, c2b, feat);
  lstm_fused<<<256, 512, 0, stream>>>(feat, wih0, whh0, bih0, bhh0,
                                      wih1, whh1, bih1, bhh1, fcw, fcb, out);
}